// Round 5
// baseline (28309.503 us; speedup 1.0000x reference)
//
#include <hip/hip_runtime.h>
#include <hip/hip_bf16.h>

// Problem constants (from the reference)
constexpr int V_ = 65, B_ = 128, T_ = 256, C_ = 384, H_ = 6, L_ = 6;
constexpr int HS_ = 64, FF_ = 4 * C_;
constexpr int BT_ = B_ * T_;
constexpr float EPS_ = 1e-5f;

// ---------------------------------------------------------------------------
// Repack wq/wk/wv [L,H,C,HS] into Wqkv [L][C][3C] with n = sec*C + h*64 + d
// so QKV becomes a single [rows,C] x [C,3C] GEMM.
// ---------------------------------------------------------------------------
__global__ __launch_bounds__(256) void repack_k(const float* __restrict__ wq,
                                                const float* __restrict__ wk,
                                                const float* __restrict__ wv,
                                                float* __restrict__ wqkv) {
  int i = blockIdx.x * 256 + threadIdx.x;          // over L*C*3C (exact)
  int n = i % (3 * C_);
  int lc = i / (3 * C_);
  int c = lc % C_;
  int l = lc / C_;
  int sec = n / C_;
  int within = n - sec * C_;
  int h = within >> 6, d = within & 63;
  const float* src = (sec == 0) ? wq : (sec == 1) ? wk : wv;
  wqkv[i] = src[(((size_t)l * H_ + h) * C_ + c) * HS_ + d];
}

// ---------------------------------------------------------------------------
// x[bt,c] = tok_emb[idx[bt],c] + pos_emb[t,c]   (float4 over C)
// ---------------------------------------------------------------------------
__global__ __launch_bounds__(256) void embed_k(const float* __restrict__ tok,
                                               const float* __restrict__ pos,
                                               const int* __restrict__ idx,
                                               float* __restrict__ x) {
  int i = blockIdx.x * 256 + threadIdx.x;          // float4 index over BT*C/4
  int c4 = i % (C_ / 4);
  int bt = i / (C_ / 4);
  int t = bt % T_;
  int tokid = idx[bt];
  float4 te = *(const float4*)(tok + (size_t)tokid * C_ + c4 * 4);
  float4 pe = *(const float4*)(pos + (size_t)t * C_ + c4 * 4);
  float4 o;
  o.x = te.x + pe.x; o.y = te.y + pe.y; o.z = te.z + pe.z; o.w = te.w + pe.w;
  *(float4*)(x + (size_t)bt * C_ + c4 * 4) = o;
}

// ---------------------------------------------------------------------------
// LayerNorm: one wave per row of C=384 (6 elems/lane)
// ---------------------------------------------------------------------------
__global__ __launch_bounds__(256) void ln_k(const float* __restrict__ x,
                                            const float* __restrict__ s,
                                            const float* __restrict__ b,
                                            float* __restrict__ out) {
  int row = blockIdx.x * 4 + (threadIdx.x >> 6);
  int lane = threadIdx.x & 63;
  const float* r = x + (size_t)row * C_;
  float v[6], sum = 0.f, sq = 0.f;
#pragma unroll
  for (int i = 0; i < 6; ++i) {
    v[i] = r[lane + i * 64];
    sum += v[i];
    sq += v[i] * v[i];
  }
#pragma unroll
  for (int o = 32; o; o >>= 1) {
    sum += __shfl_xor(sum, o, 64);
    sq += __shfl_xor(sq, o, 64);
  }
  float mean = sum * (1.f / C_);
  float var = sq * (1.f / C_) - mean * mean;
  float rstd = rsqrtf(var + EPS_);
  float* orow = out + (size_t)row * C_;
#pragma unroll
  for (int i = 0; i < 6; ++i) {
    int c = lane + i * 64;
    orow[c] = (v[i] - mean) * rstd * s[c] + b[c];
  }
}

// ---------------------------------------------------------------------------
// Generic fp32 GEMM: C = [res +] A*B [+ bias], [relu]
// A [M,K] row-major, B [K,N] row-major. M%128==0, N%128==0, K%16==0.
// 128x128 tile, BK=16, 256 threads, 8x8 per thread (2x2 blocks of 4x4).
// ---------------------------------------------------------------------------
constexpr int GBM = 128, GBN = 128, GBK = 16;

template <bool HAS_BIAS, bool DO_RELU, bool HAS_RES>
__global__ __launch_bounds__(256) void gemm_f32(const float* __restrict__ A,
                                                const float* __restrict__ Bm,
                                                const float* __restrict__ bias,
                                                const float* __restrict__ res,
                                                float* __restrict__ Cm,
                                                int M, int N, int K) {
  __shared__ float As[GBK][GBM + 4];  // row stride 132 floats (16B aligned)
  __shared__ float Bs[GBK][GBN];
  const int bm = blockIdx.y * GBM;
  const int bn = blockIdx.x * GBN;
  const int tid = threadIdx.x;
  const int tx = tid & 15;
  const int ty = tid >> 4;
  float acc[2][2][4][4];
#pragma unroll
  for (int a = 0; a < 2; ++a)
#pragma unroll
    for (int b = 0; b < 2; ++b)
#pragma unroll
      for (int i = 0; i < 4; ++i)
#pragma unroll
        for (int j = 0; j < 4; ++j) acc[a][b][i][j] = 0.f;

  for (int k0 = 0; k0 < K; k0 += GBK) {
#pragma unroll
    for (int i = 0; i < 2; ++i) {  // A tile: 128x16 = 512 float4
      int f = tid + i * 256;
      int r = f >> 2, c4 = f & 3;
      float4 av = *(const float4*)(A + (size_t)(bm + r) * K + k0 + c4 * 4);
      As[c4 * 4 + 0][r] = av.x;
      As[c4 * 4 + 1][r] = av.y;
      As[c4 * 4 + 2][r] = av.z;
      As[c4 * 4 + 3][r] = av.w;
    }
#pragma unroll
    for (int i = 0; i < 2; ++i) {  // B tile: 16x128 = 512 float4
      int f = tid + i * 256;
      int r = f >> 5, c4 = f & 31;
      *(float4*)(&Bs[r][c4 * 4]) =
          *(const float4*)(Bm + (size_t)(k0 + r) * N + bn + c4 * 4);
    }
    __syncthreads();
#pragma unroll
    for (int kk = 0; kk < GBK; ++kk) {
      float4 a0 = *(const float4*)(&As[kk][ty * 4]);
      float4 a1 = *(const float4*)(&As[kk][ty * 4 + 64]);
      float4 b0 = *(const float4*)(&Bs[kk][tx * 4]);
      float4 b1 = *(const float4*)(&Bs[kk][tx * 4 + 64]);
      float a_[2][4] = {{a0.x, a0.y, a0.z, a0.w}, {a1.x, a1.y, a1.z, a1.w}};
      float b_[2][4] = {{b0.x, b0.y, b0.z, b0.w}, {b1.x, b1.y, b1.z, b1.w}};
#pragma unroll
      for (int mi = 0; mi < 2; ++mi)
#pragma unroll
        for (int ni = 0; ni < 2; ++ni)
#pragma unroll
          for (int i = 0; i < 4; ++i)
#pragma unroll
            for (int j = 0; j < 4; ++j)
              acc[mi][ni][i][j] = fmaf(a_[mi][i], b_[ni][j], acc[mi][ni][i][j]);
    }
    __syncthreads();
  }
#pragma unroll
  for (int mi = 0; mi < 2; ++mi)
#pragma unroll
    for (int i = 0; i < 4; ++i) {
      int row = bm + ty * 4 + mi * 64 + i;
#pragma unroll
      for (int ni = 0; ni < 2; ++ni) {
        int col = bn + tx * 4 + ni * 64;
        float4 o;
        o.x = acc[mi][ni][i][0];
        o.y = acc[mi][ni][i][1];
        o.z = acc[mi][ni][i][2];
        o.w = acc[mi][ni][i][3];
        if (HAS_BIAS) {
          float4 bi = *(const float4*)(bias + col);
          o.x += bi.x; o.y += bi.y; o.z += bi.z; o.w += bi.w;
        }
        if (HAS_RES) {
          float4 rv = *(const float4*)(res + (size_t)row * N + col);
          o.x += rv.x; o.y += rv.y; o.z += rv.z; o.w += rv.w;
        }
        if (DO_RELU) {
          o.x = fmaxf(o.x, 0.f); o.y = fmaxf(o.y, 0.f);
          o.z = fmaxf(o.z, 0.f); o.w = fmaxf(o.w, 0.f);
        }
        *(float4*)(Cm + (size_t)row * N + col) = o;
      }
    }
}

// ---------------------------------------------------------------------------
// Attention over ONE chunk of batches. qkv is [chRows, 3C] with q|k|v
// sections, each head-blocked (col = h*64 + d). One wave per (b_local,h,t).
// Output att[row, h*64+d] (chunk-local rows). scale = C^-0.5 (n_embed!).
// ---------------------------------------------------------------------------
__global__ __launch_bounds__(256) void attn_k(const float* __restrict__ qkv,
                                              float* __restrict__ att) {
  __shared__ float p[4][T_];
  __shared__ float4 qs[4][HS_ / 4];
  int w = threadIdx.x >> 6, lane = threadIdx.x & 63;
  int flat = blockIdx.x * 4 + w;  // = (b_local*H + h)*T + t
  int t = flat & (T_ - 1);
  int h = (flat >> 8) % H_;
  int b = flat / (T_ * H_);       // chunk-local batch
  const float scale = 0.05103103630798288f;  // 384^-0.5 (n_embed, per reference)
  const float* qb = qkv + (size_t)b * T_ * (3 * C_);
  ((float*)qs[w])[lane] = qb[(size_t)t * (3 * C_) + h * 64 + lane];

  float lm = -INFINITY;
  for (int s = lane; s <= t; s += 64) {
    const float4* kr = (const float4*)(qb + (size_t)s * (3 * C_) + C_ + h * 64);
    float d = 0.f;
#pragma unroll
    for (int c = 0; c < 16; ++c) {
      float4 kv = kr[c];
      float4 qv = qs[w][c];
      d = fmaf(qv.x, kv.x, fmaf(qv.y, kv.y, fmaf(qv.z, kv.z, fmaf(qv.w, kv.w, d))));
    }
    d *= scale;
    p[w][s] = d;
    lm = fmaxf(lm, d);
  }
#pragma unroll
  for (int o = 32; o; o >>= 1) lm = fmaxf(lm, __shfl_xor(lm, o, 64));
  float lsum = 0.f;
  for (int s = lane; s <= t; s += 64) {
    float e = expf(p[w][s] - lm);
    p[w][s] = e;
    lsum += e;
  }
#pragma unroll
  for (int o = 32; o; o >>= 1) lsum += __shfl_xor(lsum, o, 64);
  float inv = 1.f / lsum;

  float acc = 0.f;
  const float* vb = qb + 2 * C_ + h * 64 + lane;
  for (int s = 0; s <= t; ++s) acc = fmaf(p[w][s], vb[(size_t)s * (3 * C_)], acc);
  att[((size_t)b * T_ + t) * C_ + h * 64 + lane] = acc * inv;
}

// ---------------------------------------------------------------------------
// Head: logits[row, v] = xf[row,:] . head_w[:,v] + head_b[v]; V=65.
// One wave per row: lane owns col=lane, all lanes redundantly do col 64.
// ---------------------------------------------------------------------------
__global__ __launch_bounds__(256) void head_k(const float* __restrict__ xf,
                                              const float* __restrict__ hw,
                                              const float* __restrict__ hb,
                                              float* __restrict__ out) {
  int row = blockIdx.x * 4 + (threadIdx.x >> 6);
  int lane = threadIdx.x & 63;
  const float* xr = xf + (size_t)row * C_;
  float acc = 0.f, acc64 = 0.f;
  for (int c = 0; c < C_; ++c) {
    float xv = xr[c];
    acc = fmaf(xv, hw[c * V_ + lane], acc);
    acc64 = fmaf(xv, hw[c * V_ + 64], acc64);
  }
  out[(size_t)row * V_ + lane] = acc + hb[lane];
  if (lane == 0) out[(size_t)row * V_ + 64] = acc64 + hb[64];
}

// ---------------------------------------------------------------------------
// Per-row cross-entropy: rl[row] = logsumexp(logits[row]) - logits[row,tgt]
// ---------------------------------------------------------------------------
__global__ __launch_bounds__(256) void loss_rows_k(const float* __restrict__ logits,
                                                   const int* __restrict__ tgt,
                                                   float* __restrict__ rl) {
  int row = blockIdx.x * 4 + (threadIdx.x >> 6);
  int lane = threadIdx.x & 63;
  const float* lr = logits + (size_t)row * V_;
  float v = lr[lane];
  float v64 = lr[64];
  float m = fmaxf(v, v64);
#pragma unroll
  for (int o = 32; o; o >>= 1) m = fmaxf(m, __shfl_xor(m, o, 64));
  float e = expf(v - m) + ((lane == 0) ? expf(v64 - m) : 0.f);
#pragma unroll
  for (int o = 32; o; o >>= 1) e += __shfl_xor(e, o, 64);
  int tg = tgt[row];
  float lt = (tg == 64) ? v64 : __shfl(v, tg, 64);
  if (lane == 0) rl[row] = m + logf(e) - lt;
}

// Deterministic single-block reduction -> loss scalar
__global__ __launch_bounds__(256) void reduce_loss_k(const float* __restrict__ rl,
                                                     float* __restrict__ out) {
  __shared__ float sm[256];
  float s = 0.f;
  for (int i = threadIdx.x; i < BT_; i += 256) s += rl[i];
  sm[threadIdx.x] = s;
  __syncthreads();
  for (int o = 128; o; o >>= 1) {
    if ((int)threadIdx.x < o) sm[threadIdx.x] += sm[threadIdx.x + o];
    __syncthreads();
  }
  if (threadIdx.x == 0) out[0] = sm[0] * (1.f / BT_);
}

// ---------------------------------------------------------------------------
extern "C" void kernel_launch(void* const* d_in, const int* in_sizes, int n_in,
                              void* d_out, int out_size, void* d_ws, size_t ws_size,
                              hipStream_t stream) {
  const float* tok_emb = (const float*)d_in[0];
  const float* pos_emb = (const float*)d_in[1];
  const float* wq = (const float*)d_in[2];
  const float* wk = (const float*)d_in[3];
  const float* wv = (const float*)d_in[4];
  const float* proj_w = (const float*)d_in[5];
  const float* proj_b = (const float*)d_in[6];
  const float* ln1_s = (const float*)d_in[7];
  const float* ln1_b = (const float*)d_in[8];
  const float* w1 = (const float*)d_in[9];
  const float* b1 = (const float*)d_in[10];
  const float* w2 = (const float*)d_in[11];
  const float* b2 = (const float*)d_in[12];
  const float* ln2_s = (const float*)d_in[13];
  const float* ln2_b = (const float*)d_in[14];
  const float* lnf_s = (const float*)d_in[15];
  const float* lnf_b = (const float*)d_in[16];
  const float* head_w = (const float*)d_in[17];
  const float* head_b = (const float*)d_in[18];
  const int* idx = (const int*)d_in[19];
  const int* targets = (const int*)d_in[20];
  float* out = (float*)d_out;

  // Pick the largest chunk (in batches) whose workspace fits ws_size.
  // Layout (floats): x[BT*C] | wqkv[L*C*3C] | xn_ch[chRows*C] | big[chRows*FF] | rl[BT]
  int chB = 0;
  for (int cand = 16; cand >= 1; cand >>= 1) {
    size_t need = (size_t)BT_ * C_ + (size_t)L_ * C_ * 3 * C_ +
                  (size_t)cand * T_ * C_ + (size_t)cand * T_ * FF_ + BT_;
    if (need * sizeof(float) <= ws_size) { chB = cand; break; }
  }
  if (chB == 0) return;  // fail clean (poisoned output), not OOB
  const int chRows = chB * T_;
  const int nCh = B_ / chB;

  float* x = (float*)d_ws;
  float* wqkv = x + (size_t)BT_ * C_;
  float* xn = wqkv + (size_t)L_ * C_ * 3 * C_;   // chunk-local LN out / attn out
  float* big = xn + (size_t)chRows * C_;         // chunk qkv / mlp hidden
  float* rl = big + (size_t)chRows * FF_;

  repack_k<<<(L_ * C_ * 3 * C_) / 256, 256, 0, stream>>>(wq, wk, wv, wqkv);
  embed_k<<<(BT_ * C_ / 4) / 256, 256, 0, stream>>>(tok_emb, pos_emb, idx, x);

  for (int l = 0; l < L_; ++l) {
    // --- attention half (per chunk: LN -> QKV gemm -> attn -> proj+residual)
    for (int ch = 0; ch < nCh; ++ch) {
      const size_t base = (size_t)ch * chRows;
      ln_k<<<chRows / 4, 256, 0, stream>>>(x + base * C_, ln1_s + l * C_,
                                           ln1_b + l * C_, xn);
      gemm_f32<false, false, false>
          <<<dim3(3 * C_ / GBN, chRows / GBM), 256, 0, stream>>>(
              xn, wqkv + (size_t)l * C_ * 3 * C_, nullptr, nullptr, big,
              chRows, 3 * C_, C_);
      attn_k<<<chB * H_ * T_ / 4, 256, 0, stream>>>(big, xn);
      gemm_f32<true, false, true>
          <<<dim3(C_ / GBN, chRows / GBM), 256, 0, stream>>>(
              xn, proj_w + (size_t)l * C_ * C_, proj_b + l * C_,
              x + base * C_, x + base * C_, chRows, C_, C_);
    }
    // --- MLP half (per chunk: LN -> W1+relu -> W2+residual)
    for (int ch = 0; ch < nCh; ++ch) {
      const size_t base = (size_t)ch * chRows;
      ln_k<<<chRows / 4, 256, 0, stream>>>(x + base * C_, ln2_s + l * C_,
                                           ln2_b + l * C_, xn);
      gemm_f32<true, true, false>
          <<<dim3(FF_ / GBN, chRows / GBM), 256, 0, stream>>>(
              xn, w1 + (size_t)l * C_ * FF_, b1 + l * FF_, nullptr, big,
              chRows, FF_, C_);
      gemm_f32<true, false, true>
          <<<dim3(C_ / GBN, chRows / GBM), 256, 0, stream>>>(
              big, w2 + (size_t)l * FF_ * C_, b2 + l * C_, x + base * C_,
              x + base * C_, chRows, C_, FF_);
    }
  }
  // Final LN + head + loss (per chunk for LN/head)
  for (int ch = 0; ch < B_ / chB; ++ch) {
    const size_t base = (size_t)ch * chRows;
    ln_k<<<chRows / 4, 256, 0, stream>>>(x + base * C_, lnf_s, lnf_b, xn);
    head_k<<<chRows / 4, 256, 0, stream>>>(xn, head_w, head_b,
                                           out + base * V_);
  }
  loss_rows_k<<<BT_ / 4, 256, 0, stream>>>(out, targets, rl);
  reduce_loss_k<<<1, 256, 0, stream>>>(rl, out + (size_t)BT_ * V_);
}

// Round 11
// 10816.867 us; speedup vs baseline: 2.6172x; 2.6172x over previous
//
#include <hip/hip_runtime.h>
#include <hip/hip_bf16.h>

// Problem constants (from the reference)
constexpr int V_ = 65, B_ = 128, T_ = 256, C_ = 384, H_ = 6, L_ = 6;
constexpr int HS_ = 64, FF_ = 4 * C_;
constexpr int BT_ = B_ * T_;
constexpr float EPS_ = 1e-5f;

typedef unsigned short u16;
typedef __attribute__((ext_vector_type(8))) short short8;
typedef __attribute__((ext_vector_type(4))) float f32x4;

__device__ inline u16 f2bf(float f) {  // round-to-nearest-even
  unsigned u = __float_as_uint(f);
  u += 0x7FFFu + ((u >> 16) & 1u);
  return (u16)(u >> 16);
}
__device__ inline float bf2f(u16 h) {
  return __uint_as_float(((unsigned)h) << 16);
}
__device__ inline void load16_lds(const void* g, void* l) {
  __builtin_amdgcn_global_load_lds(
      (const __attribute__((address_space(1))) void*)g,
      (__attribute__((address_space(3))) void*)l, 16, 0, 0);
}

// ---------------------------------------------------------------------------
// ONE layer: wq/wk/wv [H,C,HS] -> wqkvT [3C][C] bf16 (row n = sec*C + h*64 + d)
// Block per (sec, h, k0/64). FIXED: write loop covers all 64x64 = 4096
// elements (was 1024 -> 3/4 of weights stayed 0xAA poison; rounds 6/7/9 bug).
// ---------------------------------------------------------------------------
__global__ __launch_bounds__(256) void qkvT_k(const float* __restrict__ wq,
                                              const float* __restrict__ wk,
                                              const float* __restrict__ wv,
                                              u16* __restrict__ out) {
  __shared__ float lds[64][65];
  int b = blockIdx.x;
  int k0i = b % (C_ / 64);
  int h = (b / (C_ / 64)) % H_;
  int sec = b / (C_ / 64 * H_);
  const float* src0 = (sec == 0) ? wq : (sec == 1) ? wk : wv;
  const float* src = src0 + ((size_t)h * C_ + k0i * 64) * 64;  // [64 k][64 d]
  int t = threadIdx.x;
#pragma unroll
  for (int i = 0; i < 4; ++i) {  // load in[kk][d]: 4*256*4 = 4096 elems
    int kk = (t >> 4) + i * 16;
    int d4 = (t & 15) * 4;
    float4 v = *(const float4*)(src + (size_t)kk * 64 + d4);
    lds[kk][d4] = v.x; lds[kk][d4 + 1] = v.y;
    lds[kk][d4 + 2] = v.z; lds[kk][d4 + 3] = v.w;
  }
  __syncthreads();
  u16* ob = out + ((size_t)sec * C_ + h * 64) * C_ + k0i * 64;
#pragma unroll
  for (int i = 0; i < 16; ++i) {  // write out[d][kk]: 16*256 = 4096 elems
    int f = i * 256 + t;
    int d = f >> 6, kk = f & 63;
    ob[(size_t)d * C_ + kk] = f2bf(lds[kk][d]);
  }
}

// ---------------------------------------------------------------------------
// ONE layer: [K][N] f32 -> [N][K] bf16 transpose-convert. FIXED write loop.
// ---------------------------------------------------------------------------
__global__ __launch_bounds__(256) void transT_k(const float* __restrict__ in,
                                                u16* __restrict__ out,
                                                int K, int N) {
  __shared__ float lds[64][65];
  int nt = N / 64;
  int b = blockIdx.x;
  int n0 = (b % nt) * 64;
  int k0 = (b / nt) * 64;
  const float* src = in + (size_t)k0 * N + n0;
  int t = threadIdx.x;
#pragma unroll
  for (int i = 0; i < 4; ++i) {  // load in[kk][d]: 4096 elems
    int kk = (t >> 4) + i * 16;
    int d4 = (t & 15) * 4;
    float4 v = *(const float4*)(src + (size_t)kk * N + d4);
    lds[kk][d4] = v.x; lds[kk][d4 + 1] = v.y;
    lds[kk][d4 + 2] = v.z; lds[kk][d4 + 3] = v.w;
  }
  __syncthreads();
  u16* ob = out + (size_t)n0 * K + k0;
#pragma unroll
  for (int i = 0; i < 16; ++i) {  // write out[d][kk]: 4096 elems
    int f = i * 256 + t;
    int d = f >> 6, kk = f & 63;
    ob[(size_t)d * K + kk] = f2bf(lds[kk][d]);
  }
}

// ---------------------------------------------------------------------------
// x[bt,c] = tok_emb[idx[bt],c] + pos_emb[t,c]   (float4 over C)
// ---------------------------------------------------------------------------
__global__ __launch_bounds__(256) void embed_k(const float* __restrict__ tok,
                                               const float* __restrict__ pos,
                                               const int* __restrict__ idx,
                                               float* __restrict__ x) {
  int i = blockIdx.x * 256 + threadIdx.x;
  int c4 = i % (C_ / 4);
  int bt = i / (C_ / 4);
  int t = bt % T_;
  int tokid = idx[bt];
  float4 te = *(const float4*)(tok + (size_t)tokid * C_ + c4 * 4);
  float4 pe = *(const float4*)(pos + (size_t)t * C_ + c4 * 4);
  float4 o;
  o.x = te.x + pe.x; o.y = te.y + pe.y; o.z = te.z + pe.z; o.w = te.w + pe.w;
  *(float4*)(x + (size_t)bt * C_ + c4 * 4) = o;
}

// ---------------------------------------------------------------------------
// LayerNorm: one wave per row; fp32 in, bf16 out (GEMM A operand)
// ---------------------------------------------------------------------------
__global__ __launch_bounds__(256) void ln_bf_k(const float* __restrict__ x,
                                               const float* __restrict__ s,
                                               const float* __restrict__ b,
                                               u16* __restrict__ out) {
  int row = blockIdx.x * 4 + (threadIdx.x >> 6);
  int lane = threadIdx.x & 63;
  const float* r = x + (size_t)row * C_;
  float v[6], sum = 0.f, sq = 0.f;
#pragma unroll
  for (int i = 0; i < 6; ++i) {
    v[i] = r[lane + i * 64];
    sum += v[i];
    sq += v[i] * v[i];
  }
#pragma unroll
  for (int o = 32; o; o >>= 1) {
    sum += __shfl_xor(sum, o, 64);
    sq += __shfl_xor(sq, o, 64);
  }
  float mean = sum * (1.f / C_);
  float var = sq * (1.f / C_) - mean * mean;
  float rstd = rsqrtf(var + EPS_);
  u16* orow = out + (size_t)row * C_;
#pragma unroll
  for (int i = 0; i < 6; ++i) {
    int c = lane + i * 64;
    orow[c] = f2bf((v[i] - mean) * rstd * s[c] + b[c]);
  }
}

// ---------------------------------------------------------------------------
// bf16 MFMA GEMM: C = [res +] A*B^T [+ bias] [relu]  (m97 linear-LDS pattern)
// A [M,K] bf16 row-major, Bt [N,K] bf16 row-major (= B transposed).
// 128x128 tile, BK=64, 256 thr (2x2 waves, 64x64 out each), 16x16x32 MFMA.
// EPI: 0 = f32 out; 1 = +bias +res, f32 out; 2 = +bias, relu, bf16 out.
// ---------------------------------------------------------------------------
template <int EPI>
__global__ __launch_bounds__(256) void gemm_bf16(
    const u16* __restrict__ A, const u16* __restrict__ Bt,
    const float* __restrict__ bias, const float* __restrict__ res,
    float* __restrict__ Cf, u16* __restrict__ Cb,
    int M, int N, int K) {
  __shared__ u16 As[128 * 64];
  __shared__ u16 Bs[128 * 64];
  const int tid = threadIdx.x;
  const int lane = tid & 63, wid = tid >> 6;
  const int wm = wid >> 1, wn = wid & 1;
  const int bm = blockIdx.y * 128, bn = blockIdx.x * 128;

  f32x4 acc[4][4];
#pragma unroll
  for (int i = 0; i < 4; ++i)
#pragma unroll
    for (int j = 0; j < 4; ++j)
#pragma unroll
      for (int e = 0; e < 4; ++e) acc[i][j][e] = 0.f;

  int srow[4], scol[4];
#pragma unroll
  for (int j = 0; j < 4; ++j) {
    int gl = (j * 4 + wid) * 64 + lane;  // linear LDS granule
    srow[j] = gl >> 3;
    scol[j] = (gl & 7) * 8;
  }
  const int kg = lane >> 4, rl16 = lane & 15;

  for (int kt = 0; kt < K; kt += 64) {
    __syncthreads();  // previous tile fully consumed
#pragma unroll
    for (int j = 0; j < 4; ++j) {
      load16_lds(A + (size_t)(bm + srow[j]) * K + kt + scol[j],
                 (char*)As + ((j * 4 + wid) << 10));
      load16_lds(Bt + (size_t)(bn + srow[j]) * K + kt + scol[j],
                 (char*)Bs + ((j * 4 + wid) << 10));
    }
    __syncthreads();  // compiler drains vmcnt(0) before barrier: tile ready
#pragma unroll
    for (int s = 0; s < 2; ++s) {
      short8 av[4], bv[4];
      const int gg = (s * 4 + kg) << 4;
#pragma unroll
      for (int f = 0; f < 4; ++f) {
        int ra = wm * 64 + f * 16 + rl16;
        int rb = wn * 64 + f * 16 + rl16;
        av[f] = *(const short8*)((const char*)As + ra * 128 + gg);
        bv[f] = *(const short8*)((const char*)Bs + rb * 128 + gg);
      }
#pragma unroll
      for (int mf = 0; mf < 4; ++mf)
#pragma unroll
        for (int nf = 0; nf < 4; ++nf)
          acc[mf][nf] = __builtin_amdgcn_mfma_f32_16x16x32_bf16(
              av[mf], bv[nf], acc[mf][nf], 0, 0, 0);
    }
  }
  // epilogue: D col=lane&15, row=(lane>>4)*4+reg  (m89/m91-verified)
#pragma unroll
  for (int nf = 0; nf < 4; ++nf) {
    int gcol = bn + wn * 64 + nf * 16 + rl16;
    float bv = 0.f;
    if (EPI > 0) bv = bias[gcol];
#pragma unroll
    for (int mf = 0; mf < 4; ++mf) {
      int grow0 = bm + wm * 64 + mf * 16 + kg * 4;
#pragma unroll
      for (int i = 0; i < 4; ++i) {
        int grow = grow0 + i;
        float v = acc[mf][nf][i] + bv;
        if (EPI == 1) v += res[(size_t)grow * N + gcol];
        if (EPI == 2) {
          v = fmaxf(v, 0.f);
          Cb[(size_t)grow * N + gcol] = f2bf(v);
        } else {
          Cf[(size_t)grow * N + gcol] = v;
        }
      }
    }
  }
}

// ---------------------------------------------------------------------------
// Attention over ONE chunk. qkv [chRows, 3C] f32, q|k|v head-blocked
// (col = h*64+d). One wave per (b_local,h,t). bf16 out (feeds proj GEMM).
// scale = C^-0.5 (n_embed, per reference!)
// ---------------------------------------------------------------------------
__global__ __launch_bounds__(256) void attn_k(const float* __restrict__ qkv,
                                              u16* __restrict__ att) {
  __shared__ float p[4][T_];
  __shared__ float4 qs[4][HS_ / 4];
  int w = threadIdx.x >> 6, lane = threadIdx.x & 63;
  int flat = blockIdx.x * 4 + w;  // = (b_local*H + h)*T + t
  int t = flat & (T_ - 1);
  int h = (flat >> 8) % H_;
  int b = flat / (T_ * H_);
  const float scale = 0.05103103630798288f;  // 384^-0.5
  const float* qb = qkv + (size_t)b * T_ * (3 * C_);
  ((float*)qs[w])[lane] = qb[(size_t)t * (3 * C_) + h * 64 + lane];

  float lm = -INFINITY;
  for (int s = lane; s <= t; s += 64) {
    const float4* kr = (const float4*)(qb + (size_t)s * (3 * C_) + C_ + h * 64);
    float d = 0.f;
#pragma unroll
    for (int c = 0; c < 16; ++c) {
      float4 kv = kr[c];
      float4 qv = qs[w][c];
      d = fmaf(qv.x, kv.x, fmaf(qv.y, kv.y, fmaf(qv.z, kv.z, fmaf(qv.w, kv.w, d))));
    }
    d *= scale;
    p[w][s] = d;
    lm = fmaxf(lm, d);
  }
#pragma unroll
  for (int o = 32; o; o >>= 1) lm = fmaxf(lm, __shfl_xor(lm, o, 64));
  float lsum = 0.f;
  for (int s = lane; s <= t; s += 64) {
    float e = expf(p[w][s] - lm);
    p[w][s] = e;
    lsum += e;
  }
#pragma unroll
  for (int o = 32; o; o >>= 1) lsum += __shfl_xor(lsum, o, 64);
  float inv = 1.f / lsum;

  float acc = 0.f;
  const float* vb = qb + 2 * C_ + h * 64 + lane;
  for (int s = 0; s <= t; ++s) acc = fmaf(p[w][s], vb[(size_t)s * (3 * C_)], acc);
  att[((size_t)b * T_ + t) * C_ + h * 64 + lane] = f2bf(acc * inv);
}

// ---------------------------------------------------------------------------
// Head: logits[row,v] = xf[row,:].head_w[:,v] + head_b[v]; xf bf16, V=65
// ---------------------------------------------------------------------------
__global__ __launch_bounds__(256) void head_k(const u16* __restrict__ xf,
                                              const float* __restrict__ hw,
                                              const float* __restrict__ hb,
                                              float* __restrict__ out) {
  int row = blockIdx.x * 4 + (threadIdx.x >> 6);
  int lane = threadIdx.x & 63;
  const u16* xr = xf + (size_t)row * C_;
  float acc = 0.f, acc64 = 0.f;
  for (int c = 0; c < C_; ++c) {
    float xv = bf2f(xr[c]);
    acc = fmaf(xv, hw[c * V_ + lane], acc);
    acc64 = fmaf(xv, hw[c * V_ + 64], acc64);
  }
  out[(size_t)row * V_ + lane] = acc + hb[lane];
  if (lane == 0) out[(size_t)row * V_ + 64] = acc64 + hb[64];
}

// ---------------------------------------------------------------------------
// Per-row cross-entropy + deterministic reduction
// ---------------------------------------------------------------------------
__global__ __launch_bounds__(256) void loss_rows_k(const float* __restrict__ logits,
                                                   const int* __restrict__ tgt,
                                                   float* __restrict__ rl) {
  int row = blockIdx.x * 4 + (threadIdx.x >> 6);
  int lane = threadIdx.x & 63;
  const float* lr = logits + (size_t)row * V_;
  float v = lr[lane];
  float v64 = lr[64];
  float m = fmaxf(v, v64);
#pragma unroll
  for (int o = 32; o; o >>= 1) m = fmaxf(m, __shfl_xor(m, o, 64));
  float e = expf(v - m) + ((lane == 0) ? expf(v64 - m) : 0.f);
#pragma unroll
  for (int o = 32; o; o >>= 1) e += __shfl_xor(e, o, 64);
  int tg = tgt[row];
  float lt = (tg == 64) ? v64 : __shfl(v, tg, 64);
  if (lane == 0) rl[row] = m + logf(e) - lt;
}

__global__ __launch_bounds__(256) void reduce_loss_k(const float* __restrict__ rl,
                                                     float* __restrict__ out) {
  __shared__ float sm[256];
  float s = 0.f;
  for (int i = threadIdx.x; i < BT_; i += 256) s += rl[i];
  sm[threadIdx.x] = s;
  __syncthreads();
  for (int o = 128; o; o >>= 1) {
    if ((int)threadIdx.x < o) sm[threadIdx.x] += sm[threadIdx.x + o];
    __syncthreads();
  }
  if (threadIdx.x == 0) out[0] = sm[0] * (1.f / BT_);
}

// ---------------------------------------------------------------------------
extern "C" void kernel_launch(void* const* d_in, const int* in_sizes, int n_in,
                              void* d_out, int out_size, void* d_ws, size_t ws_size,
                              hipStream_t stream) {
  const float* tok_emb = (const float*)d_in[0];
  const float* pos_emb = (const float*)d_in[1];
  const float* wq = (const float*)d_in[2];
  const float* wk = (const float*)d_in[3];
  const float* wv = (const float*)d_in[4];
  const float* proj_w = (const float*)d_in[5];
  const float* proj_b = (const float*)d_in[6];
  const float* ln1_s = (const float*)d_in[7];
  const float* ln1_b = (const float*)d_in[8];
  const float* w1 = (const float*)d_in[9];
  const float* b1 = (const float*)d_in[10];
  const float* w2 = (const float*)d_in[11];
  const float* b2 = (const float*)d_in[12];
  const float* ln2_s = (const float*)d_in[13];
  const float* ln2_b = (const float*)d_in[14];
  const float* lnf_s = (const float*)d_in[15];
  const float* lnf_b = (const float*)d_in[16];
  const float* head_w = (const float*)d_in[17];
  const float* head_b = (const float*)d_in[18];
  const int* idx = (const int*)d_in[19];
  const int* targets = (const int*)d_in[20];
  float* out = (float*)d_out;

  // fixed: x | wqkvT(1 layer) | projT | w1T | w2T | rl  (~54 MB)
  // chunked: xn(bf16) | qkvb(f32) | hid(bf16)  (~2.1 MB per chunk-batch)
  const size_t fixedB = (size_t)BT_ * C_ * 4 +
                        ((size_t)3 * C_ * C_ + (size_t)C_ * C_ +
                         (size_t)C_ * FF_ + (size_t)FF_ * C_) * 2 +
                        (size_t)BT_ * 4;
  int chB = 0;
  for (int cand = 128; cand >= 1; cand >>= 1) {
    size_t need = fixedB + (size_t)cand * T_ * (C_ * 2 + 3 * C_ * 4 + FF_ * 2);
    if (need <= ws_size) { chB = cand; break; }
  }
  if (chB == 0) return;  // chB=1 needs ~56 MB < round-5-proven >=63 MB
  const int chRows = chB * T_;
  const int nCh = B_ / chB;

  char* p = (char*)d_ws;
  float* x = (float*)p;      p += (size_t)BT_ * C_ * 4;
  u16* wqkvT = (u16*)p;      p += (size_t)3 * C_ * C_ * 2;
  u16* projT = (u16*)p;      p += (size_t)C_ * C_ * 2;
  u16* w1T = (u16*)p;        p += (size_t)C_ * FF_ * 2;
  u16* w2T = (u16*)p;        p += (size_t)FF_ * C_ * 2;
  float* rl = (float*)p;     p += (size_t)BT_ * 4;
  u16* xn = (u16*)p;         p += (size_t)chRows * C_ * 2;
  float* qkvb = (float*)p;   p += (size_t)chRows * 3 * C_ * 4;
  u16* hid = (u16*)p;

  embed_k<<<(BT_ * C_ / 4) / 256, 256, 0, stream>>>(tok_emb, pos_emb, idx, x);

  for (int l = 0; l < L_; ++l) {
    // per-layer weight convert (graph-safe: identical work every call)
    qkvT_k<<<3 * H_ * (C_ / 64), 256, 0, stream>>>(
        wq + (size_t)l * H_ * C_ * HS_, wk + (size_t)l * H_ * C_ * HS_,
        wv + (size_t)l * H_ * C_ * HS_, wqkvT);
    transT_k<<<(C_ / 64) * (C_ / 64), 256, 0, stream>>>(
        proj_w + (size_t)l * C_ * C_, projT, C_, C_);
    transT_k<<<(C_ / 64) * (FF_ / 64), 256, 0, stream>>>(
        w1 + (size_t)l * C_ * FF_, w1T, C_, FF_);
    transT_k<<<(FF_ / 64) * (C_ / 64), 256, 0, stream>>>(
        w2 + (size_t)l * FF_ * C_, w2T, FF_, C_);

    for (int ch = 0; ch < nCh; ++ch) {
      const size_t base = (size_t)ch * chRows;
      ln_bf_k<<<chRows / 4, 256, 0, stream>>>(x + base * C_, ln1_s + l * C_,
                                              ln1_b + l * C_, xn);
      gemm_bf16<0><<<dim3(3 * C_ / 128, chRows / 128), 256, 0, stream>>>(
          xn, wqkvT, nullptr, nullptr, qkvb, nullptr, chRows, 3 * C_, C_);
      attn_k<<<chB * H_ * T_ / 4, 256, 0, stream>>>(qkvb, xn);
      gemm_bf16<1><<<dim3(C_ / 128, chRows / 128), 256, 0, stream>>>(
          xn, projT, proj_b + l * C_, x + base * C_, x + base * C_, nullptr,
          chRows, C_, C_);
    }
    for (int ch = 0; ch < nCh; ++ch) {
      const size_t base = (size_t)ch * chRows;
      ln_bf_k<<<chRows / 4, 256, 0, stream>>>(x + base * C_, ln2_s + l * C_,
                                              ln2_b + l * C_, xn);
      gemm_bf16<2><<<dim3(FF_ / 128, chRows / 128), 256, 0, stream>>>(
          xn, w1T, b1 + l * FF_, nullptr, nullptr, hid, chRows, FF_, C_);
      gemm_bf16<1><<<dim3(C_ / 128, chRows / 128), 256, 0, stream>>>(
          hid, w2T, b2 + l * C_, x + base * C_, x + base * C_, nullptr,
          chRows, C_, FF_);
    }
  }
  for (int ch = 0; ch < nCh; ++ch) {
    const size_t base = (size_t)ch * chRows;
    ln_bf_k<<<chRows / 4, 256, 0, stream>>>(x + base * C_, lnf_s, lnf_b, xn);
    head_k<<<chRows / 4, 256, 0, stream>>>(xn, head_w, head_b, out + base * V_);
  }
  loss_rows_k<<<BT_ / 4, 256, 0, stream>>>(out, targets, rl);
  reduce_loss_k<<<1, 256, 0, stream>>>(rl, out + (size_t)BT_ * V_);
}

// Round 14
// 10162.260 us; speedup vs baseline: 2.7857x; 1.0644x over previous
//
#include <hip/hip_runtime.h>
#include <hip/hip_bf16.h>

// Problem constants (from the reference)
constexpr int V_ = 65, B_ = 128, T_ = 256, C_ = 384, H_ = 6, L_ = 6;
constexpr int HS_ = 64, FF_ = 4 * C_;
constexpr int BT_ = B_ * T_;
constexpr float EPS_ = 1e-5f;

typedef unsigned short u16;
typedef __attribute__((ext_vector_type(8))) short short8;
typedef __attribute__((ext_vector_type(4))) float f32x4;

__device__ inline u16 f2bf(float f) {  // round-to-nearest-even
  unsigned u = __float_as_uint(f);
  u += 0x7FFFu + ((u >> 16) & 1u);
  return (u16)(u >> 16);
}
__device__ inline float bf2f(u16 h) {
  return __uint_as_float(((unsigned)h) << 16);
}
__device__ inline void load16_lds(const void* g, void* l) {
  __builtin_amdgcn_global_load_lds(
      (const __attribute__((address_space(1))) void*)g,
      (__attribute__((address_space(3))) void*)l, 16, 0, 0);
}

// ---------------------------------------------------------------------------
// ONE layer: wq/wk/wv [H,C,HS] -> wqkvT [3C][C] bf16 (row n = sec*C + h*64 + d)
// ---------------------------------------------------------------------------
__global__ __launch_bounds__(256) void qkvT_k(const float* __restrict__ wq,
                                              const float* __restrict__ wk,
                                              const float* __restrict__ wv,
                                              u16* __restrict__ out) {
  __shared__ float lds[64][65];
  int b = blockIdx.x;
  int k0i = b % (C_ / 64);
  int h = (b / (C_ / 64)) % H_;
  int sec = b / (C_ / 64 * H_);
  const float* src0 = (sec == 0) ? wq : (sec == 1) ? wk : wv;
  const float* src = src0 + ((size_t)h * C_ + k0i * 64) * 64;  // [64 k][64 d]
  int t = threadIdx.x;
#pragma unroll
  for (int i = 0; i < 4; ++i) {  // load in[kk][d]: 4096 elems
    int kk = (t >> 4) + i * 16;
    int d4 = (t & 15) * 4;
    float4 v = *(const float4*)(src + (size_t)kk * 64 + d4);
    lds[kk][d4] = v.x; lds[kk][d4 + 1] = v.y;
    lds[kk][d4 + 2] = v.z; lds[kk][d4 + 3] = v.w;
  }
  __syncthreads();
  u16* ob = out + ((size_t)sec * C_ + h * 64) * C_ + k0i * 64;
#pragma unroll
  for (int i = 0; i < 16; ++i) {  // write out[d][kk]: 4096 elems
    int f = i * 256 + t;
    int d = f >> 6, kk = f & 63;
    ob[(size_t)d * C_ + kk] = f2bf(lds[kk][d]);
  }
}

// ---------------------------------------------------------------------------
// ONE layer: [K][N] f32 -> [N][K] bf16 transpose-convert (K,N mult of 64)
// ---------------------------------------------------------------------------
__global__ __launch_bounds__(256) void transT_k(const float* __restrict__ in,
                                                u16* __restrict__ out,
                                                int K, int N) {
  __shared__ float lds[64][65];
  int nt = N / 64;
  int b = blockIdx.x;
  int n0 = (b % nt) * 64;
  int k0 = (b / nt) * 64;
  const float* src = in + (size_t)k0 * N + n0;
  int t = threadIdx.x;
#pragma unroll
  for (int i = 0; i < 4; ++i) {
    int kk = (t >> 4) + i * 16;
    int d4 = (t & 15) * 4;
    float4 v = *(const float4*)(src + (size_t)kk * N + d4);
    lds[kk][d4] = v.x; lds[kk][d4 + 1] = v.y;
    lds[kk][d4 + 2] = v.z; lds[kk][d4 + 3] = v.w;
  }
  __syncthreads();
  u16* ob = out + (size_t)n0 * K + k0;
#pragma unroll
  for (int i = 0; i < 16; ++i) {
    int f = i * 256 + t;
    int d = f >> 6, kk = f & 63;
    ob[(size_t)d * K + kk] = f2bf(lds[kk][d]);
  }
}

// ---------------------------------------------------------------------------
// x[bt,c] = tok_emb[idx[bt],c] + pos_emb[t,c]   (float4 over C)
// ---------------------------------------------------------------------------
__global__ __launch_bounds__(256) void embed_k(const float* __restrict__ tok,
                                               const float* __restrict__ pos,
                                               const int* __restrict__ idx,
                                               float* __restrict__ x) {
  int i = blockIdx.x * 256 + threadIdx.x;
  int c4 = i % (C_ / 4);
  int bt = i / (C_ / 4);
  int t = bt % T_;
  int tokid = idx[bt];
  float4 te = *(const float4*)(tok + (size_t)tokid * C_ + c4 * 4);
  float4 pe = *(const float4*)(pos + (size_t)t * C_ + c4 * 4);
  float4 o;
  o.x = te.x + pe.x; o.y = te.y + pe.y; o.z = te.z + pe.z; o.w = te.w + pe.w;
  *(float4*)(x + (size_t)bt * C_ + c4 * 4) = o;
}

// ---------------------------------------------------------------------------
// LayerNorm: one wave per row; fp32 in, bf16 out (GEMM A operand)
// ---------------------------------------------------------------------------
__global__ __launch_bounds__(256) void ln_bf_k(const float* __restrict__ x,
                                               const float* __restrict__ s,
                                               const float* __restrict__ b,
                                               u16* __restrict__ out) {
  int row = blockIdx.x * 4 + (threadIdx.x >> 6);
  int lane = threadIdx.x & 63;
  const float* r = x + (size_t)row * C_;
  float v[6], sum = 0.f, sq = 0.f;
#pragma unroll
  for (int i = 0; i < 6; ++i) {
    v[i] = r[lane + i * 64];
    sum += v[i];
    sq += v[i] * v[i];
  }
#pragma unroll
  for (int o = 32; o; o >>= 1) {
    sum += __shfl_xor(sum, o, 64);
    sq += __shfl_xor(sq, o, 64);
  }
  float mean = sum * (1.f / C_);
  float var = sq * (1.f / C_) - mean * mean;
  float rstd = rsqrtf(var + EPS_);
  u16* orow = out + (size_t)row * C_;
#pragma unroll
  for (int i = 0; i < 6; ++i) {
    int c = lane + i * 64;
    orow[c] = f2bf((v[i] - mean) * rstd * s[c] + b[c]);
  }
}

// ---------------------------------------------------------------------------
// bf16 MFMA GEMM: C = [res +] A*B^T [+ bias] [relu]  (m97 linear-LDS pattern)
// A [M,K] bf16 row-major, Bt [N,K] bf16 row-major (= B transposed).
// 128x128 tile, BK=64, 256 thr (2x2 waves, 64x64 out each), 16x16x32 MFMA.
// EPI: 0 = f32 out; 1 = +bias +res, f32 out; 2 = +bias, relu, bf16 out.
// ---------------------------------------------------------------------------
template <int EPI>
__global__ __launch_bounds__(256) void gemm_bf16(
    const u16* __restrict__ A, const u16* __restrict__ Bt,
    const float* __restrict__ bias, const float* __restrict__ res,
    float* __restrict__ Cf, u16* __restrict__ Cb,
    int M, int N, int K) {
  __shared__ u16 As[128 * 64];
  __shared__ u16 Bs[128 * 64];
  const int tid = threadIdx.x;
  const int lane = tid & 63, wid = tid >> 6;
  const int wm = wid >> 1, wn = wid & 1;
  const int bm = blockIdx.y * 128, bn = blockIdx.x * 128;

  f32x4 acc[4][4];
#pragma unroll
  for (int i = 0; i < 4; ++i)
#pragma unroll
    for (int j = 0; j < 4; ++j)
#pragma unroll
      for (int e = 0; e < 4; ++e) acc[i][j][e] = 0.f;

  int srow[4], scol[4];
#pragma unroll
  for (int j = 0; j < 4; ++j) {
    int gl = (j * 4 + wid) * 64 + lane;  // linear LDS granule
    srow[j] = gl >> 3;
    scol[j] = (gl & 7) * 8;
  }
  const int kg = lane >> 4, rl16 = lane & 15;

  for (int kt = 0; kt < K; kt += 64) {
    __syncthreads();  // previous tile fully consumed
#pragma unroll
    for (int j = 0; j < 4; ++j) {
      load16_lds(A + (size_t)(bm + srow[j]) * K + kt + scol[j],
                 (char*)As + ((j * 4 + wid) << 10));
      load16_lds(Bt + (size_t)(bn + srow[j]) * K + kt + scol[j],
                 (char*)Bs + ((j * 4 + wid) << 10));
    }
    __syncthreads();  // compiler drains vmcnt(0) before barrier: tile ready
#pragma unroll
    for (int s = 0; s < 2; ++s) {
      short8 av[4], bv[4];
      const int gg = (s * 4 + kg) << 4;
#pragma unroll
      for (int f = 0; f < 4; ++f) {
        int ra = wm * 64 + f * 16 + rl16;
        int rb = wn * 64 + f * 16 + rl16;
        av[f] = *(const short8*)((const char*)As + ra * 128 + gg);
        bv[f] = *(const short8*)((const char*)Bs + rb * 128 + gg);
      }
#pragma unroll
      for (int mf = 0; mf < 4; ++mf)
#pragma unroll
        for (int nf = 0; nf < 4; ++nf)
          acc[mf][nf] = __builtin_amdgcn_mfma_f32_16x16x32_bf16(
              av[mf], bv[nf], acc[mf][nf], 0, 0, 0);
    }
  }
  // epilogue: D col=lane&15, row=(lane>>4)*4+reg  (m89/m91-verified)
#pragma unroll
  for (int nf = 0; nf < 4; ++nf) {
    int gcol = bn + wn * 64 + nf * 16 + rl16;
    float bv = 0.f;
    if (EPI > 0) bv = bias[gcol];
#pragma unroll
    for (int mf = 0; mf < 4; ++mf) {
      int grow0 = bm + wm * 64 + mf * 16 + kg * 4;
#pragma unroll
      for (int i = 0; i < 4; ++i) {
        int grow = grow0 + i;
        float v = acc[mf][nf][i] + bv;
        if (EPI == 1) v += res[(size_t)grow * N + gcol];
        if (EPI == 2) {
          v = fmaxf(v, 0.f);
          Cb[(size_t)grow * N + gcol] = f2bf(v);
        } else {
          Cf[(size_t)grow * N + gcol] = v;
        }
      }
    }
  }
}

// ---------------------------------------------------------------------------
// Attention over ONE chunk. qkv [chRows, 3C] f32, q|k|v head-blocked
// (col = h*64+d). One wave per (b_local,h,t). bf16 out (feeds proj GEMM).
// scale = C^-0.5 (n_embed, per reference!)
// ROUND-12: ILP fixes — QK dot uses 4 parallel partial chains; PV uses
// 8 independent accumulators (8 loads in flight instead of 1 serial chain).
// ---------------------------------------------------------------------------
__global__ __launch_bounds__(256) void attn_k(const float* __restrict__ qkv,
                                              u16* __restrict__ att) {
  __shared__ float p[4][T_];
  __shared__ float4 qs[4][HS_ / 4];
  int w = threadIdx.x >> 6, lane = threadIdx.x & 63;
  int flat = blockIdx.x * 4 + w;  // = (b_local*H + h)*T + t
  int t = flat & (T_ - 1);
  int h = (flat >> 8) % H_;
  int b = flat / (T_ * H_);
  const float scale = 0.05103103630798288f;  // 384^-0.5
  const float* qb = qkv + (size_t)b * T_ * (3 * C_);
  ((float*)qs[w])[lane] = qb[(size_t)t * (3 * C_) + h * 64 + lane];

  float lm = -INFINITY;
  for (int s = lane; s <= t; s += 64) {
    const float4* kr = (const float4*)(qb + (size_t)s * (3 * C_) + C_ + h * 64);
    float d0 = 0.f, d1 = 0.f, d2 = 0.f, d3 = 0.f;  // 4 parallel chains
#pragma unroll
    for (int c = 0; c < 16; ++c) {
      float4 kv = kr[c];
      float4 qv = qs[w][c];
      d0 = fmaf(qv.x, kv.x, d0);
      d1 = fmaf(qv.y, kv.y, d1);
      d2 = fmaf(qv.z, kv.z, d2);
      d3 = fmaf(qv.w, kv.w, d3);
    }
    float d = ((d0 + d1) + (d2 + d3)) * scale;
    p[w][s] = d;
    lm = fmaxf(lm, d);
  }
#pragma unroll
  for (int o = 32; o; o >>= 1) lm = fmaxf(lm, __shfl_xor(lm, o, 64));
  float lsum = 0.f;
  for (int s = lane; s <= t; s += 64) {
    float e = expf(p[w][s] - lm);
    p[w][s] = e;
    lsum += e;
  }
#pragma unroll
  for (int o = 32; o; o >>= 1) lsum += __shfl_xor(lsum, o, 64);
  float inv = 1.f / lsum;

  // PV: 8 independent accumulators -> 8 loads in flight
  const float* vb = qb + 2 * C_ + h * 64 + lane;
  const float* pw = p[w];
  const int n = t + 1;
  float a0 = 0.f, a1 = 0.f, a2 = 0.f, a3 = 0.f;
  float a4 = 0.f, a5 = 0.f, a6 = 0.f, a7 = 0.f;
  int s = 0;
  for (; s + 8 <= n; s += 8) {
    float v0 = vb[(size_t)(s + 0) * (3 * C_)];
    float v1 = vb[(size_t)(s + 1) * (3 * C_)];
    float v2 = vb[(size_t)(s + 2) * (3 * C_)];
    float v3 = vb[(size_t)(s + 3) * (3 * C_)];
    float v4 = vb[(size_t)(s + 4) * (3 * C_)];
    float v5 = vb[(size_t)(s + 5) * (3 * C_)];
    float v6 = vb[(size_t)(s + 6) * (3 * C_)];
    float v7 = vb[(size_t)(s + 7) * (3 * C_)];
    a0 = fmaf(pw[s + 0], v0, a0);
    a1 = fmaf(pw[s + 1], v1, a1);
    a2 = fmaf(pw[s + 2], v2, a2);
    a3 = fmaf(pw[s + 3], v3, a3);
    a4 = fmaf(pw[s + 4], v4, a4);
    a5 = fmaf(pw[s + 5], v5, a5);
    a6 = fmaf(pw[s + 6], v6, a6);
    a7 = fmaf(pw[s + 7], v7, a7);
  }
  for (; s < n; ++s) a0 = fmaf(pw[s], vb[(size_t)s * (3 * C_)], a0);
  float acc = ((a0 + a1) + (a2 + a3)) + ((a4 + a5) + (a6 + a7));
  att[((size_t)b * T_ + t) * C_ + h * 64 + lane] = f2bf(acc * inv);
}

// ---------------------------------------------------------------------------
// Head: logits[row,v] = xf[row,:].head_w[:,v] + head_b[v]; xf bf16, V=65
// ---------------------------------------------------------------------------
__global__ __launch_bounds__(256) void head_k(const u16* __restrict__ xf,
                                              const float* __restrict__ hw,
                                              const float* __restrict__ hb,
                                              float* __restrict__ out) {
  int row = blockIdx.x * 4 + (threadIdx.x >> 6);
  int lane = threadIdx.x & 63;
  const u16* xr = xf + (size_t)row * C_;
  float acc = 0.f, acc64 = 0.f;
  for (int c = 0; c < C_; ++c) {
    float xv = bf2f(xr[c]);
    acc = fmaf(xv, hw[c * V_ + lane], acc);
    acc64 = fmaf(xv, hw[c * V_ + 64], acc64);
  }
  out[(size_t)row * V_ + lane] = acc + hb[lane];
  if (lane == 0) out[(size_t)row * V_ + 64] = acc64 + hb[64];
}

// ---------------------------------------------------------------------------
// Per-row cross-entropy + deterministic reduction
// ---------------------------------------------------------------------------
__global__ __launch_bounds__(256) void loss_rows_k(const float* __restrict__ logits,
                                                   const int* __restrict__ tgt,
                                                   float* __restrict__ rl) {
  int row = blockIdx.x * 4 + (threadIdx.x >> 6);
  int lane = threadIdx.x & 63;
  const float* lr = logits + (size_t)row * V_;
  float v = lr[lane];
  float v64 = lr[64];
  float m = fmaxf(v, v64);
#pragma unroll
  for (int o = 32; o; o >>= 1) m = fmaxf(m, __shfl_xor(m, o, 64));
  float e = expf(v - m) + ((lane == 0) ? expf(v64 - m) : 0.f);
#pragma unroll
  for (int o = 32; o; o >>= 1) e += __shfl_xor(e, o, 64);
  int tg = tgt[row];
  float lt = (tg == 64) ? v64 : __shfl(v, tg, 64);
  if (lane == 0) rl[row] = m + logf(e) - lt;
}

__global__ __launch_bounds__(256) void reduce_loss_k(const float* __restrict__ rl,
                                                     float* __restrict__ out) {
  __shared__ float sm[256];
  float s = 0.f;
  for (int i = threadIdx.x; i < BT_; i += 256) s += rl[i];
  sm[threadIdx.x] = s;
  __syncthreads();
  for (int o = 128; o; o >>= 1) {
    if ((int)threadIdx.x < o) sm[threadIdx.x] += sm[threadIdx.x + o];
    __syncthreads();
  }
  if (threadIdx.x == 0) out[0] = sm[0] * (1.f / BT_);
}

// ---------------------------------------------------------------------------
extern "C" void kernel_launch(void* const* d_in, const int* in_sizes, int n_in,
                              void* d_out, int out_size, void* d_ws, size_t ws_size,
                              hipStream_t stream) {
  const float* tok_emb = (const float*)d_in[0];
  const float* pos_emb = (const float*)d_in[1];
  const float* wq = (const float*)d_in[2];
  const float* wk = (const float*)d_in[3];
  const float* wv = (const float*)d_in[4];
  const float* proj_w = (const float*)d_in[5];
  const float* proj_b = (const float*)d_in[6];
  const float* ln1_s = (const float*)d_in[7];
  const float* ln1_b = (const float*)d_in[8];
  const float* w1 = (const float*)d_in[9];
  const float* b1 = (const float*)d_in[10];
  const float* w2 = (const float*)d_in[11];
  const float* b2 = (const float*)d_in[12];
  const float* ln2_s = (const float*)d_in[13];
  const float* ln2_b = (const float*)d_in[14];
  const float* lnf_s = (const float*)d_in[15];
  const float* lnf_b = (const float*)d_in[16];
  const float* head_w = (const float*)d_in[17];
  const float* head_b = (const float*)d_in[18];
  const int* idx = (const int*)d_in[19];
  const int* targets = (const int*)d_in[20];
  float* out = (float*)d_out;

  // fixed: x | wqkvT(1 layer) | projT | w1T | w2T | rl  (~54 MB)
  // chunked: xn(bf16) | qkvb(f32) | hid(bf16)  (~2.1 MB per chunk-batch)
  const size_t fixedB = (size_t)BT_ * C_ * 4 +
                        ((size_t)3 * C_ * C_ + (size_t)C_ * C_ +
                         (size_t)C_ * FF_ + (size_t)FF_ * C_) * 2 +
                        (size_t)BT_ * 4;
  int chB = 0;
  for (int cand = 128; cand >= 1; cand >>= 1) {
    size_t need = fixedB + (size_t)cand * T_ * (C_ * 2 + 3 * C_ * 4 + FF_ * 2);
    if (need <= ws_size) { chB = cand; break; }
  }
  if (chB == 0) return;  // fail clean, not OOB
  const int chRows = chB * T_;
  const int nCh = B_ / chB;

  char* p = (char*)d_ws;
  float* x = (float*)p;      p += (size_t)BT_ * C_ * 4;
  u16* wqkvT = (u16*)p;      p += (size_t)3 * C_ * C_ * 2;
  u16* projT = (u16*)p;      p += (size_t)C_ * C_ * 2;
  u16* w1T = (u16*)p;        p += (size_t)C_ * FF_ * 2;
  u16* w2T = (u16*)p;        p += (size_t)FF_ * C_ * 2;
  float* rl = (float*)p;     p += (size_t)BT_ * 4;
  u16* xn = (u16*)p;         p += (size_t)chRows * C_ * 2;
  float* qkvb = (float*)p;   p += (size_t)chRows * 3 * C_ * 4;
  u16* hid = (u16*)p;

  embed_k<<<(BT_ * C_ / 4) / 256, 256, 0, stream>>>(tok_emb, pos_emb, idx, x);

  for (int l = 0; l < L_; ++l) {
    // per-layer weight convert (graph-safe: identical work every call)
    qkvT_k<<<3 * H_ * (C_ / 64), 256, 0, stream>>>(
        wq + (size_t)l * H_ * C_ * HS_, wk + (size_t)l * H_ * C_ * HS_,
        wv + (size_t)l * H_ * C_ * HS_, wqkvT);
    transT_k<<<(C_ / 64) * (C_ / 64), 256, 0, stream>>>(
        proj_w + (size_t)l * C_ * C_, projT, C_, C_);
    transT_k<<<(C_ / 64) * (FF_ / 64), 256, 0, stream>>>(
        w1 + (size_t)l * C_ * FF_, w1T, C_, FF_);
    transT_k<<<(FF_ / 64) * (C_ / 64), 256, 0, stream>>>(
        w2 + (size_t)l * FF_ * C_, w2T, FF_, C_);

    for (int ch = 0; ch < nCh; ++ch) {
      const size_t base = (size_t)ch * chRows;
      ln_bf_k<<<chRows / 4, 256, 0, stream>>>(x + base * C_, ln1_s + l * C_,
                                              ln1_b + l * C_, xn);
      gemm_bf16<0><<<dim3(3 * C_ / 128, chRows / 128), 256, 0, stream>>>(
          xn, wqkvT, nullptr, nullptr, qkvb, nullptr, chRows, 3 * C_, C_);
      attn_k<<<chB * H_ * T_ / 4, 256, 0, stream>>>(qkvb, xn);
      gemm_bf16<1><<<dim3(C_ / 128, chRows / 128), 256, 0, stream>>>(
          xn, projT, proj_b + l * C_, x + base * C_, x + base * C_, nullptr,
          chRows, C_, C_);
    }
    for (int ch = 0; ch < nCh; ++ch) {
      const size_t base = (size_t)ch * chRows;
      ln_bf_k<<<chRows / 4, 256, 0, stream>>>(x + base * C_, ln2_s + l * C_,
                                              ln2_b + l * C_, xn);
      gemm_bf16<2><<<dim3(FF_ / 128, chRows / 128), 256, 0, stream>>>(
          xn, w1T, b1 + l * FF_, nullptr, nullptr, hid, chRows, FF_, C_);
      gemm_bf16<1><<<dim3(C_ / 128, chRows / 128), 256, 0, stream>>>(
          hid, w2T, b2 + l * C_, x + base * C_, x + base * C_, nullptr,
          chRows, C_, FF_);
    }
  }
  for (int ch = 0; ch < nCh; ++ch) {
    const size_t base = (size_t)ch * chRows;
    ln_bf_k<<<chRows / 4, 256, 0, stream>>>(x + base * C_, lnf_s, lnf_b, xn);
    head_k<<<chRows / 4, 256, 0, stream>>>(xn, head_w, head_b, out + base * V_);
  }
  loss_rows_k<<<BT_ / 4, 256, 0, stream>>>(out, targets, rl);
  reduce_loss_k<<<1, 256, 0, stream>>>(rl, out + (size_t)BT_ * V_);
}